// Round 4
// baseline (431.626 us; speedup 1.0000x reference)
//
#include <hip/hip_runtime.h>
#include <math.h>

#define Lseq 2048
// B=16, L=2048, H=8, E=64, O=64, MODES=64 (index_q = index_kv = arange)
// Radix-2: f = m < 64. t = t' + 1024j:
//   even f: y_e = x[t'] + x[t'+1024]; odd f: y_o = x[t'] - x[t'+1024]
// G[e,m] = sum_{t'<1024} y_{par(m)}[e,t'] * (cos,-sin)
// fp16 MFMA with hi/lo split on BOTH operands (3 MFMAs): operand error
// ~2^-22 rel; residual dominated by fp32 accumulation (same as fp32 path).

typedef _Float16 f16;
typedef _Float16 f16x2 __attribute__((ext_vector_type(2)));
typedef _Float16 f16x8 __attribute__((ext_vector_type(8)));
typedef float    f32x4 __attribute__((ext_vector_type(4)));

// ---------------- workspace layout (bytes) ----------------
// tw32 [512][64] float2            256 KB  fp32 irfft twiddles
// tf16: 8 tables [64 n][1024 t'] f16, 128 KB each = 1 MB
//   table idx = z*4 + cls*2 + part   (z: 0=q 1=k, cls: 0=even 1=odd, part: 0=hi 1=lo)
// Gq/Gk [128 bh][64 e][64 m] cplx  4 MB each ; U 4 MB ; A 4 MB
// Gp [512 slots][64 e][128 col] f32  16 MB  split-K partials
#define OFF_TW32 0u
#define OFF_TF16 0x40000u
#define OFF_GQ   (2u << 20)
#define OFF_GK   (6u << 20)
#define OFF_U    (10u << 20)
#define OFF_A    (14u << 20)
#define OFF_GP   (18u << 20)

// ---------------------------------------------------------------------------
__global__ __launch_bounds__(256) void k_twiddle(
    const int* __restrict__ iq, const int* __restrict__ ikv,
    float2* __restrict__ tw32, f16* __restrict__ tf)
{
    int gid = blockIdx.x * 256 + threadIdx.x;    // 65536 = 1024 t' x 64 m
    int t = gid >> 6, m = gid & 63;
    const float w = 6.2831853071795864769f / (float)Lseq;
    int cls = m & 1;
    int j2 = (m >> 1) * 2;
    float s, c;
    // q tables
    sincosf(w * (float)((t * iq[m]) & (Lseq - 1)), &s, &c);
    {
        f16* hi = tf + (size_t)(0 * 4 + cls * 2 + 0) * 65536;
        f16* lo = tf + (size_t)(0 * 4 + cls * 2 + 1) * 65536;
        f16 ch = (f16)c, sh = (f16)s;
        hi[j2 * 1024 + t] = ch;          lo[j2 * 1024 + t] = (f16)(c - (float)ch);
        hi[(j2 + 1) * 1024 + t] = sh;    lo[(j2 + 1) * 1024 + t] = (f16)(s - (float)sh);
    }
    if (t < 512) tw32[t * 64 + m] = make_float2(c, s);   // irfft table (f=iq)
    // k tables
    sincosf(w * (float)((t * ikv[m]) & (Lseq - 1)), &s, &c);
    {
        f16* hi = tf + (size_t)(1 * 4 + cls * 2 + 0) * 65536;
        f16* lo = tf + (size_t)(1 * 4 + cls * 2 + 1) * 65536;
        f16 ch = (f16)c, sh = (f16)s;
        hi[j2 * 1024 + t] = ch;          lo[j2 * 1024 + t] = (f16)(c - (float)ch);
        hi[(j2 + 1) * 1024 + t] = sh;    lo[(j2 + 1) * 1024 + t] = (f16)(s - (float)sh);
    }
}

// ---------------------------------------------------------------------------
// MFMA DFT with hi/lo split. grid (b, h, zc): z = zc>>1, chunk = zc&1.
// 256 thr = 4 waves; waves 0,1 even class, 2,3 odd. Per k-step (32 t'):
// stage A(hi,lo) + B(hi,lo) tiles (XOR-swizzled 16B blocks), 1 barrier,
// 3 MFMAs per (mt,nt): AhiBhi + AloBhi + AhiBlo.
__global__ __launch_bounds__(256) void k_dft(
    const float* __restrict__ q, const float* __restrict__ k,
    const f16* __restrict__ tf, float* __restrict__ Gp)
{
    int b = blockIdx.x, h = blockIdx.y, zc = blockIdx.z;
    int z = zc >> 1, chunk = zc & 1;
    const float* src = z ? k : q;
    const f16* tEhi = tf + (size_t)(z * 4 + 0) * 65536;
    const f16* tElo = tf + (size_t)(z * 4 + 1) * 65536;
    const f16* tOhi = tf + (size_t)(z * 4 + 2) * 65536;
    const f16* tOlo = tf + (size_t)(z * 4 + 3) * 65536;

    // tiles: 0=AeHi 1=AeLo 2=AoHi 3=AoLo 4=BeHi 5=BeLo 6=BoHi 7=BoLo
    __shared__ __align__(16) f16 sm[2][8][2048];   // 64 KB

    int tid = threadIdx.x;
    int l = tid & 63, w = tid >> 6;

    int a_ = tid & 15, tp = tid >> 4;                 // signal: e4=4a_, t'pair=2tp
    const float* xbase = src + ((size_t)b * Lseq) * 512 + h * 64 + a_ * 4;
    int bn = tid >> 2, bblk = tid & 3;                // B staging: row n, 8-f16 block

    int cls = w >> 1, wl = w & 1;

    f32x4 acc[4][2];
#pragma unroll
    for (int i = 0; i < 4; ++i)
#pragma unroll
        for (int j = 0; j < 2; ++j) acc[i][j] = (f32x4)0.0f;

    float4 r0, r1, r2, r3;
    f16x8 bEh, bEl, bOh, bOl;
    {   // prefetch step 0
        int t0 = chunk * 512;
        const float* p = xbase + (size_t)(t0 + 2 * tp) * 512;
        r0 = *(const float4*)(p);
        r1 = *(const float4*)(p + 512);
        r2 = *(const float4*)(p + 1024 * 512);
        r3 = *(const float4*)(p + 1024 * 512 + 512);
        int boff = bn * 1024 + t0 + bblk * 8;
        bEh = *(const f16x8*)(tEhi + boff);
        bEl = *(const f16x8*)(tElo + boff);
        bOh = *(const f16x8*)(tOhi + boff);
        bOl = *(const f16x8*)(tOlo + boff);
    }

    for (int kk = 0; kk < 16; ++kk) {
        int p_ = kk & 1;

        float ye_a[4], ye_b[4], yo_a[4], yo_b[4];
        const float* f0 = (const float*)&r0;
        const float* f1 = (const float*)&r1;
        const float* f2 = (const float*)&r2;
        const float* f3 = (const float*)&r3;
#pragma unroll
        for (int i = 0; i < 4; ++i) {
            ye_a[i] = f0[i] + f2[i];  ye_b[i] = f1[i] + f3[i];
            yo_a[i] = f0[i] - f2[i];  yo_b[i] = f1[i] - f3[i];
        }
#pragma unroll
        for (int i = 0; i < 4; ++i) {
            int e = a_ * 4 + i;
            int blks = (tp >> 2) ^ ((e >> 2) & 3);
            int off = e * 32 + blks * 8 + (tp & 3) * 2;
            f16x2 hi, lo;
            hi.x = (f16)ye_a[i]; hi.y = (f16)ye_b[i];
            lo.x = (f16)(ye_a[i] - (float)hi.x); lo.y = (f16)(ye_b[i] - (float)hi.y);
            *(f16x2*)&sm[p_][0][off] = hi;
            *(f16x2*)&sm[p_][1][off] = lo;
            hi.x = (f16)yo_a[i]; hi.y = (f16)yo_b[i];
            lo.x = (f16)(yo_a[i] - (float)hi.x); lo.y = (f16)(yo_b[i] - (float)hi.y);
            *(f16x2*)&sm[p_][2][off] = hi;
            *(f16x2*)&sm[p_][3][off] = lo;
        }
        {
            int blks = bblk ^ ((bn >> 2) & 3);
            int off = bn * 32 + blks * 8;
            *(f16x8*)&sm[p_][4][off] = bEh;
            *(f16x8*)&sm[p_][5][off] = bEl;
            *(f16x8*)&sm[p_][6][off] = bOh;
            *(f16x8*)&sm[p_][7][off] = bOl;
        }
        if (kk < 15) {   // prefetch next step (in flight across barrier)
            int t0 = chunk * 512 + (kk + 1) * 32;
            const float* p = xbase + (size_t)(t0 + 2 * tp) * 512;
            r0 = *(const float4*)(p);
            r1 = *(const float4*)(p + 512);
            r2 = *(const float4*)(p + 1024 * 512);
            r3 = *(const float4*)(p + 1024 * 512 + 512);
            int boff = bn * 1024 + t0 + bblk * 8;
            bEh = *(const f16x8*)(tEhi + boff);
            bEl = *(const f16x8*)(tElo + boff);
            bOh = *(const f16x8*)(tOhi + boff);
            bOl = *(const f16x8*)(tOlo + boff);
        }
        __syncthreads();

        const f16* Ahi = &sm[p_][cls ? 2 : 0][0];
        const f16* Alo = &sm[p_][cls ? 3 : 1][0];
        const f16* Bhi = &sm[p_][cls ? 6 : 4][0];
        const f16* Blo = &sm[p_][cls ? 7 : 5][0];
        f16x8 bfh[2], bfl[2];
#pragma unroll
        for (int nt = 0; nt < 2; ++nt) {
            int n = wl * 32 + nt * 16 + (l & 15);
            int blks = (l >> 4) ^ ((n >> 2) & 3);
            bfh[nt] = *(const f16x8*)&Bhi[n * 32 + blks * 8];
            bfl[nt] = *(const f16x8*)&Blo[n * 32 + blks * 8];
        }
#pragma unroll
        for (int mt = 0; mt < 4; ++mt) {
            int e = mt * 16 + (l & 15);
            int blks = (l >> 4) ^ ((e >> 2) & 3);
            f16x8 afh = *(const f16x8*)&Ahi[e * 32 + blks * 8];
            f16x8 afl = *(const f16x8*)&Alo[e * 32 + blks * 8];
#pragma unroll
            for (int nt = 0; nt < 2; ++nt) {
                acc[mt][nt] = __builtin_amdgcn_mfma_f32_16x16x32_f16(
                    afh, bfh[nt], acc[mt][nt], 0, 0, 0);
                acc[mt][nt] = __builtin_amdgcn_mfma_f32_16x16x32_f16(
                    afl, bfh[nt], acc[mt][nt], 0, 0, 0);
                acc[mt][nt] = __builtin_amdgcn_mfma_f32_16x16x32_f16(
                    afh, bfl[nt], acc[mt][nt], 0, 0, 0);
            }
        }
    }

    int slot = ((z * 16 + b) * 8 + h) * 2 + chunk;
    float* gp = Gp + (size_t)slot * 8192;
    int lcol = l & 15, lrow = (l >> 4) * 4;
#pragma unroll
    for (int mt = 0; mt < 4; ++mt)
#pragma unroll
        for (int nt = 0; nt < 2; ++nt) {
            int col = cls * 64 + wl * 32 + nt * 16 + lcol;
#pragma unroll
            for (int r = 0; r < 4; ++r)
                gp[(size_t)(mt * 16 + lrow + r) * 128 + col] = acc[mt][nt][r];
        }
}

// ---------------------------------------------------------------------------
// Sum the 2 chunk partials, remap (class,col) -> G[e][m] = (Re, -Im).
__global__ __launch_bounds__(256) void k_reduce(
    const float* __restrict__ Gp, float2* __restrict__ Gq, float2* __restrict__ Gk)
{
    int gid = blockIdx.x * 256 + threadIdx.x;   // 1,048,576
    int zbh = gid >> 12;
    int rem = gid & 4095;
    int e = rem >> 6, m = rem & 63;
    int cls = m & 1, j = m >> 1;
    int col = cls * 64 + 2 * j;
    const float* base = Gp + (size_t)zbh * 2 * 8192;
    float re = base[e * 128 + col]     + base[8192 + e * 128 + col];
    float im = base[e * 128 + col + 1] + base[8192 + e * 128 + col + 1];
    float2* dst = (zbh < 128) ? Gq : Gk;
    dst[(size_t)(zbh & 127) * 4096 + e * 64 + m] = make_float2(re, -im);
}

// ---------------------------------------------------------------------------
// Per (b,h): freq-domain projection of q,k; S = Q^T K; tanh; U = T K. (fp32)
__global__ __launch_bounds__(256) void k_core(
    const float2* __restrict__ Gq, const float2* __restrict__ Gk,
    const float* __restrict__ wqw, const float* __restrict__ wqb,
    const float* __restrict__ wkw, const float* __restrict__ wkb,
    const int* __restrict__ iq, const int* __restrict__ ikv,
    float2* __restrict__ U)
{
    int b = blockIdx.x, h = blockIdx.y;
    int tid = threadIdx.x;
    __shared__ float2 bufA[4096];
    __shared__ float2 Qf[4096];
    __shared__ float2 Kf[4096];
    __shared__ float  Wm[4096];
    __shared__ float  bias_s[64];
    __shared__ int    idx_s[64];

    size_t gb = (size_t)(b * 8 + h) * 4096;

    for (int z = 0; z < 2; ++z) {
        const float* Wsrc = z ? wkw : wqw;
        const float* bsrc = z ? wkb : wqb;
        const int*   isrc = z ? ikv : iq;
        const float2* Gsrc = (z ? Gk : Gq) + gb;
        float2* dst = z ? Kf : Qf;
        if (tid < 64) { bias_s[tid] = bsrc[tid]; idx_s[tid] = isrc[tid]; }
#pragma unroll
        for (int j = 0; j < 4; ++j)
            ((float4*)Wm)[tid + 256 * j] = ((const float4*)Wsrc)[tid + 256 * j];
#pragma unroll
        for (int j = 0; j < 8; ++j)
            ((float4*)bufA)[tid + 256 * j] = ((const float4*)Gsrc)[tid + 256 * j];
        __syncthreads();
        {
            int eg = tid >> 4, xg = tid & 15;
            float2 acc[4][4];
#pragma unroll
            for (int i = 0; i < 4; ++i)
#pragma unroll
                for (int j = 0; j < 4; ++j) acc[i][j] = make_float2(0.f, 0.f);
            for (int ep = 0; ep < 64; ++ep) {
                float wv[4]; float2 gvv[4];
#pragma unroll
                for (int i = 0; i < 4; ++i) wv[i] = Wm[(eg * 4 + i) * 64 + ep];
#pragma unroll
                for (int j = 0; j < 4; ++j) gvv[j] = bufA[ep * 64 + xg + 16 * j];
#pragma unroll
                for (int i = 0; i < 4; ++i)
#pragma unroll
                    for (int j = 0; j < 4; ++j) {
                        acc[i][j].x += wv[i] * gvv[j].x;
                        acc[i][j].y += wv[i] * gvv[j].y;
                    }
            }
#pragma unroll
            for (int j = 0; j < 4; ++j) {
                int x = xg + 16 * j;
                float bz = (idx_s[x] == 0) ? 2048.0f : 0.0f;
#pragma unroll
                for (int i = 0; i < 4; ++i) {
                    float2 v = acc[i][j];
                    v.x += bz * bias_s[eg * 4 + i];
                    dst[(eg * 4 + i) * 64 + x] = v;
                }
            }
        }
        __syncthreads();
    }

    {
        int xg = tid & 15, yg = tid >> 4;
        float2 acc[4][4];
#pragma unroll
        for (int i = 0; i < 4; ++i)
#pragma unroll
            for (int j = 0; j < 4; ++j) acc[i][j] = make_float2(0.f, 0.f);
        for (int e = 0; e < 64; ++e) {
            float2 qv[4], kv[4];
#pragma unroll
            for (int i = 0; i < 4; ++i) qv[i] = Qf[e * 64 + xg + 16 * i];
#pragma unroll
            for (int j = 0; j < 4; ++j) kv[j] = Kf[e * 64 + yg * 4 + j];
#pragma unroll
            for (int i = 0; i < 4; ++i)
#pragma unroll
                for (int j = 0; j < 4; ++j) {
                    acc[i][j].x += qv[i].x * kv[j].x - qv[i].y * kv[j].y;
                    acc[i][j].y += qv[i].x * kv[j].y + qv[i].y * kv[j].x;
                }
        }
#pragma unroll
        for (int i = 0; i < 4; ++i)
#pragma unroll
            for (int j = 0; j < 4; ++j)
                bufA[(yg * 4 + j) * 64 + xg + 16 * i] =
                    make_float2(tanhf(acc[i][j].x), tanhf(acc[i][j].y));
    }
    __syncthreads();

    {
        int xg = tid & 15, eg = tid >> 4;
        float2 acc[4][4];
#pragma unroll
        for (int i = 0; i < 4; ++i)
#pragma unroll
            for (int j = 0; j < 4; ++j) acc[i][j] = make_float2(0.f, 0.f);
        for (int y = 0; y < 64; ++y) {
            float2 kv[4], tv[4];
#pragma unroll
            for (int i = 0; i < 4; ++i) kv[i] = Kf[(eg * 4 + i) * 64 + y];
#pragma unroll
            for (int j = 0; j < 4; ++j) tv[j] = bufA[y * 64 + xg + 16 * j];
#pragma unroll
            for (int i = 0; i < 4; ++i)
#pragma unroll
                for (int j = 0; j < 4; ++j) {
                    acc[i][j].x += tv[j].x * kv[i].x - tv[j].y * kv[i].y;
                    acc[i][j].y += tv[j].x * kv[i].y + tv[j].y * kv[i].x;
                }
        }
        float2* Ud = U + gb;
#pragma unroll
        for (int i = 0; i < 4; ++i)
#pragma unroll
            for (int j = 0; j < 4; ++j)
                Ud[(eg * 4 + i) * 64 + xg + 16 * j] = acc[i][j];
    }
}

// ---------------------------------------------------------------------------
// Per (h,o) block: xqkvw[b,o,x] = sum_e U[b,e,x] * (w1+iw2)[h,e,o,x];
// fold irfft scales, store A[b][h][o][x] = (P, Q). No weight pre-transpose.
__global__ __launch_bounds__(256) void k_apply_w(
    const float2* __restrict__ U, const float* __restrict__ w1,
    const float* __restrict__ w2, const int* __restrict__ iq,
    float2* __restrict__ A)
{
    int o = blockIdx.x & 63, h = blockIdx.x >> 6;
    int tid = threadIdx.x;
    __shared__ float2 w_s[4096];     // [e][x]
    {
        int e = tid >> 2, x0 = (tid & 3) * 16;
        const float* p1 = w1 + ((size_t)(h * 64 + e) * 64 + o) * 64 + x0;
        const float* p2 = w2 + ((size_t)(h * 64 + e) * 64 + o) * 64 + x0;
#pragma unroll
        for (int u = 0; u < 4; ++u) {
            float4 a4 = *(const float4*)(p1 + u * 4);
            float4 b4 = *(const float4*)(p2 + u * 4);
            w_s[e * 64 + x0 + u * 4 + 0] = make_float2(a4.x, b4.x);
            w_s[e * 64 + x0 + u * 4 + 1] = make_float2(a4.y, b4.y);
            w_s[e * 64 + x0 + u * 4 + 2] = make_float2(a4.z, b4.z);
            w_s[e * 64 + x0 + u * 4 + 3] = make_float2(a4.w, b4.w);
        }
    }
    __syncthreads();
    int x = tid & 63, bq = tid >> 6;
    int f = iq[x];
    bool dc = (f == 0) || (2 * f == Lseq);
    float cm = (dc ? 1.0f : 2.0f) * (1.0f / (2048.0f * 262144.0f));
#pragma unroll
    for (int it = 0; it < 4; ++it) {
        int bb = it * 4 + bq;
        const float2* Ub = U + (size_t)(bb * 8 + h) * 4096 + x;
        float2 acc = make_float2(0.f, 0.f);
        for (int e = 0; e < 64; ++e) {
            float2 u = Ub[e * 64];
            float2 wv = w_s[e * 64 + x];
            acc.x += u.x * wv.x - u.y * wv.y;
            acc.y += u.x * wv.y + u.y * wv.x;
        }
        A[(size_t)(bb * 8 + h) * 4096 + o * 64 + x] =
            make_float2(cm * acc.x, dc ? 0.0f : -cm * acc.y);
    }
}

// ---------------------------------------------------------------------------
// Radix-4 inverse: out[t'+512j] from class sums.
__global__ __launch_bounds__(512) void k_irfft(
    const float2* __restrict__ A, const float* __restrict__ tw,
    float* __restrict__ out)
{
    int tt = blockIdx.x, h = blockIdx.y, b = blockIdx.z;
    int t0 = tt * 64;
    int tid = threadIdx.x;
    __shared__ float2 A_s[4096];        // [o][x] (P,Q)
    __shared__ float  tw_s[64][128];    // rows t', XOR-swizzled float4s
    const float4* asrc = (const float4*)(A + (size_t)(b * 8 + h) * 4096);
#pragma unroll
    for (int j = 0; j < 4; ++j)
        ((float4*)A_s)[tid + 512 * j] = asrc[tid + 512 * j];
    {
        int row = tid >> 3, c4b = (tid & 7) * 4;
        const float4* s = (const float4*)(tw + (size_t)(t0 + row) * 128);
        float4* drow = (float4*)&tw_s[row][0];
#pragma unroll
        for (int kk = 0; kk < 4; ++kk) {
            int c4 = c4b + kk;
            drow[c4 ^ (row & 31)] = s[c4];
        }
    }
    __syncthreads();
    int tl = tid & 63, ow = tid >> 6;
    float U0[8], U1[8], V1[8], U2[8], U3[8], V3[8];
#pragma unroll
    for (int i = 0; i < 8; ++i) { U0[i]=U1[i]=V1[i]=U2[i]=U3[i]=V3[i]=0.f; }
    const float4* trow = (const float4*)&tw_s[tl][0];
    int sw = tl & 31;
#pragma unroll
    for (int g = 0; g < 16; ++g) {
        float4 w0 = trow[(2 * g) ^ sw];
        float4 w1 = trow[(2 * g + 1) ^ sw];
#pragma unroll
        for (int i = 0; i < 8; ++i) {
            const float4* ap = (const float4*)&A_s[(ow * 8 + i) * 64 + 4 * g];
            float4 a0 = ap[0];
            float4 a1 = ap[1];
            U0[i] += a0.x * w0.x + a0.y * w0.y;
            U1[i] += a0.z * w0.z + a0.w * w0.w;
            V1[i] += a0.w * w0.z - a0.z * w0.w;
            U2[i] += a1.x * w1.x + a1.y * w1.y;
            U3[i] += a1.z * w1.z + a1.w * w1.w;
            V3[i] += a1.w * w1.z - a1.z * w1.w;
        }
    }
    float* op = out + ((size_t)(b * 8 + h) * 64 + ow * 8) * Lseq + t0 + tl;
#pragma unroll
    for (int i = 0; i < 8; ++i) {
        float u0 = U0[i], u1 = U1[i], v1 = V1[i], u2 = U2[i], u3 = U3[i], v3 = V3[i];
        op[(size_t)i * Lseq +    0] = u0 + u1 + u2 + u3;
        op[(size_t)i * Lseq +  512] = u0 + v1 - u2 - v3;
        op[(size_t)i * Lseq + 1024] = u0 - u1 + u2 - u3;
        op[(size_t)i * Lseq + 1536] = u0 - v1 - u2 + v3;
    }
}

// ---------------------------------------------------------------------------
extern "C" void kernel_launch(void* const* d_in, const int* in_sizes, int n_in,
                              void* d_out, int out_size, void* d_ws, size_t ws_size,
                              hipStream_t stream)
{
    const float* q    = (const float*)d_in[0];
    const float* k    = (const float*)d_in[1];
    const float* wq_w = (const float*)d_in[3];
    const float* wq_b = (const float*)d_in[4];
    const float* wk_w = (const float*)d_in[5];
    const float* wk_b = (const float*)d_in[6];
    const float* w1   = (const float*)d_in[9];
    const float* w2   = (const float*)d_in[10];
    const int*   iq   = (const int*)d_in[11];
    const int*   ikv  = (const int*)d_in[12];
    float* out = (float*)d_out;

    char* ws = (char*)d_ws;
    float2* tw32 = (float2*)(ws + OFF_TW32);
    f16*    tf   = (f16*)(ws + OFF_TF16);
    float2* Gq = (float2*)(ws + OFF_GQ);
    float2* Gk = (float2*)(ws + OFF_GK);
    float2* Uw = (float2*)(ws + OFF_U);
    float2* Aw = (float2*)(ws + OFF_A);
    float*  GpF = (float*)(ws + OFF_GP);

    k_twiddle<<<256, 256, 0, stream>>>(iq, ikv, tw32, tf);
    k_dft<<<dim3(16, 8, 4), 256, 0, stream>>>(q, k, tf, GpF);
    k_reduce<<<4096, 256, 0, stream>>>(GpF, Gq, Gk);
    k_core<<<dim3(16, 8), 256, 0, stream>>>(Gq, Gk, wq_w, wq_b, wk_w, wk_b,
                                            iq, ikv, Uw);
    k_apply_w<<<512, 256, 0, stream>>>(Uw, w1, w2, iq, Aw);
    k_irfft<<<dim3(8, 8, 16), 512, 0, stream>>>(Aw, (const float*)tw32, out);
}